// Round 4
// baseline (479.001 us; speedup 1.0000x reference)
//
#include <hip/hip_runtime.h>
#include <math.h>

#define NB 16384
#define ND 512
#define NE 16
#define NH 2048
#define CW 64             // cols per chunk in mfma_mlp
#define NCH (NH / CW)     // 32 chunks
#define LN_EPS 1e-5f

typedef __attribute__((ext_vector_type(8))) short s8v;   // 8 bf16 (4 VGPR)
typedef __attribute__((ext_vector_type(4))) float f4v;   // mfma 16x16 acc

// ---- ws layout (bytes) ----
#define WS_XN_OFF    ((size_t)0)
#define WS_XN_BYTES  ((size_t)NB * ND * 2)                       // 16 MiB
#define WS_CNT_OFF   (WS_XN_OFF + WS_XN_BYTES)
#define WS_ROWS_OFF  (WS_CNT_OFF + 256)

__device__ __forceinline__ unsigned short bf16_rne(float f) {
    unsigned u = __float_as_uint(f);
    unsigned r = (u + 0x7fffu + ((u >> 16) & 1u)) >> 16;
    return (unsigned short)r;
}

// ---------------- Kernel 1: gate + softmax + argmax + LN + xn(bf16) -------
// One wave per row. Gate dot uses lane = expert(0..15) + 16*quarter(0..3):
// only 2 shuffles reduce the quarter dim (vs 6-level 16-value butterfly).
__global__ __launch_bounds__(256) void gate_ln_kernel(
    const float* __restrict__ z, const float* __restrict__ gw,
    const float* __restrict__ gb, const float* __restrict__ ln_s,
    const float* __restrict__ ln_b, const float* __restrict__ b2,
    unsigned short* __restrict__ xn, int* __restrict__ counts,
    int* __restrict__ rows, float* __restrict__ g_out,
    float* __restrict__ logits)
{
    int wave = threadIdx.x >> 6;
    int lane = threadIdx.x & 63;
    int b = blockIdx.x * 4 + wave;
    if (b >= NB) return;

    const float* zr = z + (size_t)b * ND;
    float4 za = *reinterpret_cast<const float4*>(zr + lane * 8);
    float4 zb = *reinterpret_cast<const float4*>(zr + lane * 8 + 4);
    float zv[8] = {za.x, za.y, za.z, za.w, zb.x, zb.y, zb.z, zb.w};

    float sum = 0.f, ssq = 0.f;
#pragma unroll
    for (int k = 0; k < 8; ++k) { sum += zv[k]; ssq += zv[k] * zv[k]; }

    // gate dot: expert eq, quarter qq
    int eq = lane & 15;
    int qq = lane >> 4;
    const float* zq = zr + qq * 128;
    const float* gq = gw + (size_t)(qq * 128) * NE + eq;
    float ga = 0.f;
#pragma unroll 8
    for (int i = 0; i < 32; ++i) {
        float4 zz = *reinterpret_cast<const float4*>(zq + i * 4);
        ga = fmaf(zz.x, gq[(size_t)(i * 4 + 0) * NE], ga);
        ga = fmaf(zz.y, gq[(size_t)(i * 4 + 1) * NE], ga);
        ga = fmaf(zz.z, gq[(size_t)(i * 4 + 2) * NE], ga);
        ga = fmaf(zz.w, gq[(size_t)(i * 4 + 3) * NE], ga);
    }
    // LN stats butterfly (6 levels x 2 values)
#pragma unroll
    for (int m = 32; m >= 1; m >>= 1) {
        sum += __shfl_xor(sum, m);
        ssq += __shfl_xor(ssq, m);
    }
    // reduce quarters: lanes {e,e+16,e+32,e+48} all end up with full dot
    ga += __shfl_xor(ga, 16);
    ga += __shfl_xor(ga, 32);
    ga += gb[eq];

    float mu = sum * (1.f / ND);
    float var = ssq * (1.f / ND) - mu * mu;
    float rstd = rsqrtf(var + LN_EPS);

    // softmax over the 16-expert dim (replicated in all 4 quarters)
    float gmax = ga;
#pragma unroll
    for (int m = 1; m < 16; m <<= 1) gmax = fmaxf(gmax, __shfl_xor(gmax, m));
    float ge = __expf(ga - gmax);
    float den = ge;
#pragma unroll
    for (int m = 1; m < 16; m <<= 1) den += __shfl_xor(den, m);
    float gval = ge / den;

    // argmax, first occurrence (lowest lane among exact-max logits)
    unsigned long long bal = __ballot((lane < 16) && (ga == gmax));
    int idx = __ffsll(bal) - 1;

    if (lane < NE) g_out[(size_t)b * NE + lane] = gval;

    // xn = ((z-mu)*rstd)*ln_s[idx] + ln_b[idx], bf16 RNE
    const float* ls = ln_s + (size_t)idx * ND;
    const float* lb = ln_b + (size_t)idx * ND;
    float4 s0 = *reinterpret_cast<const float4*>(ls + lane * 8);
    float4 s1 = *reinterpret_cast<const float4*>(ls + lane * 8 + 4);
    float4 t0 = *reinterpret_cast<const float4*>(lb + lane * 8);
    float4 t1 = *reinterpret_cast<const float4*>(lb + lane * 8 + 4);
    float lsv[8] = {s0.x, s0.y, s0.z, s0.w, s1.x, s1.y, s1.z, s1.w};
    float lbv[8] = {t0.x, t0.y, t0.z, t0.w, t1.x, t1.y, t1.z, t1.w};
    unsigned short xb[8];
#pragma unroll
    for (int k = 0; k < 8; ++k) {
        float xv = (zv[k] - mu) * rstd * lsv[k] + lbv[k];
        xb[k] = bf16_rne(xv);
    }
    *reinterpret_cast<s8v*>(xn + (size_t)b * ND + lane * 8) =
        *reinterpret_cast<s8v*>(xb);

    if (lane == 0) {
        logits[b] = b2[idx];   // init; mfma_mlp accumulates on top
        int pos = atomicAdd(counts + idx, 1);
        rows[(size_t)idx * NB + pos] = b;
    }
}

// ---------------- Kernel 2: grouped MFMA MLP ------------------------------
// grid = NE*NCH = 512 blocks of 512 threads (8 waves) -> exactly 2 blocks/CU,
// 4 waves/SIMD. e = bid&15 (expert->XCD pinning), ch = bid>>4.
// Stage 64-col w1 slice f32->bf16 transposed into swizzled LDS once; waves
// stream 64-row tiles of the expert bucket, 16 K-steps x 16 MFMA, no
// barriers in the main loop; gelu + w2 dot + shuffle reduce + atomicAdd.
__global__ __launch_bounds__(512, 4) void mfma_mlp(
    const unsigned short* __restrict__ xn, const float* __restrict__ w1,
    const float* __restrict__ b1, const float* __restrict__ w2,
    const int* __restrict__ counts, const int* __restrict__ rows,
    float* __restrict__ logits)
{
    __shared__ char lds_b[CW * ND * 2];   // 65536 B, [col][k] bf16, swizzled

    int bid = blockIdx.x;
    int e  = bid & 15;
    int ch = bid >> 4;          // 0..31
    int c0 = ch * CW;
    int tid = threadIdx.x;
    int lane = tid & 63;
    int wave = tid >> 6;        // 0..7

    // ---- stage B: w1[e][k][c0+c] -> lds_b[c][2k ^ ((c&7)<<4)] -------------
    {
        int c  = tid & 63;
        int kq = tid >> 6;                      // 0..7 -> k range of 64
        const float* src = w1 + (size_t)e * ND * NH + c0 + c;
        char* dst = lds_b + c * 1024;
        int sw = (c & 7) << 4;
        for (int k0 = kq * 64; k0 < kq * 64 + 64; k0 += 8) {
            unsigned int u[4];
#pragma unroll
            for (int p = 0; p < 4; ++p) {
                float f0 = src[(size_t)(k0 + 2 * p) * NH];
                float f1 = src[(size_t)(k0 + 2 * p + 1) * NH];
                u[p] = (unsigned)bf16_rne(f0) | ((unsigned)bf16_rne(f1) << 16);
            }
            *reinterpret_cast<uint4*>(dst + ((k0 * 2) ^ sw)) =
                make_uint4(u[0], u[1], u[2], u[3]);
        }
    }
    __syncthreads();

    int cnt = counts[e];
    const int* rl = rows + (size_t)e * NB;

    float b1v[4], w2v[4];
    int bb[4];                  // precomputed LDS byte bases per cf
#pragma unroll
    for (int cf = 0; cf < 4; ++cf) {
        int col = cf * 16 + (lane & 15);
        b1v[cf] = b1[(size_t)e * NH + c0 + col];
        w2v[cf] = w2[(size_t)e * NH + c0 + col];
        bb[cf] = col * 1024;
    }
    int g = lane >> 4;
    int sw = (lane & 7) << 4;   // col&7 == lane&7 for all cf

    for (int t = wave; t * 64 < cnt; t += 8) {
        int r0 = t * 64;
        const unsigned short* abase[4];
#pragma unroll
        for (int rf = 0; rf < 4; ++rf) {
            int rp = r0 + rf * 16 + (lane & 15);
            int rpc = rp < cnt ? rp : cnt - 1;
            abase[rf] = xn + (size_t)rl[rpc] * ND + g * 8;
        }

        f4v acc[4][4];
#pragma unroll
        for (int rf = 0; rf < 4; ++rf)
#pragma unroll
            for (int cf = 0; cf < 4; ++cf) acc[rf][cf] = (f4v){0.f, 0.f, 0.f, 0.f};

#pragma unroll
        for (int ks = 0; ks < 16; ++ks) {
            s8v a[4], b[4];
#pragma unroll
            for (int rf = 0; rf < 4; ++rf)
                a[rf] = *reinterpret_cast<const s8v*>(abase[rf] + ks * 32);
            int kb = (ks * 64 + g * 16) ^ sw;
#pragma unroll
            for (int cf = 0; cf < 4; ++cf)
                b[cf] = *reinterpret_cast<const s8v*>(lds_b + bb[cf] + kb);
#pragma unroll
            for (int rf = 0; rf < 4; ++rf)
#pragma unroll
                for (int cf = 0; cf < 4; ++cf)
                    acc[rf][cf] = __builtin_amdgcn_mfma_f32_16x16x32_bf16(
                        a[rf], b[cf], acc[rf][cf], 0, 0, 0);
        }

        // ---- epilogue: bias + gelu + w2 dot + 16-lane reduce + atomic ----
#pragma unroll
        for (int rf = 0; rf < 4; ++rf) {
            float pj[4] = {0.f, 0.f, 0.f, 0.f};
#pragma unroll
            for (int cf = 0; cf < 4; ++cf) {
#pragma unroll
                for (int j = 0; j < 4; ++j) {
                    float h = acc[rf][cf][j] + b1v[cf];
                    float u = h * (0.7978845608f + 0.0356774081f * h * h);
                    float ex = __expf(2.f * u);
                    float th = 1.f - 2.f / (ex + 1.f);
                    float gl = 0.5f * h * (1.f + th);
                    pj[j] = fmaf(gl, w2v[cf], pj[j]);
                }
            }
#pragma unroll
            for (int m = 1; m < 16; m <<= 1) {
#pragma unroll
                for (int j = 0; j < 4; ++j) pj[j] += __shfl_xor(pj[j], m);
            }
            if ((lane & 15) == 0) {
#pragma unroll
                for (int j = 0; j < 4; ++j) {
                    int rp = r0 + rf * 16 + g * 4 + j;
                    if (rp < cnt) atomicAdd(&logits[rl[rp]], pj[j]);
                }
            }
        }
    }
}

extern "C" void kernel_launch(void* const* d_in, const int* in_sizes, int n_in,
                              void* d_out, int out_size, void* d_ws, size_t ws_size,
                              hipStream_t stream) {
    const float* z    = (const float*)d_in[0];
    const float* gw   = (const float*)d_in[1];
    const float* gb   = (const float*)d_in[2];
    const float* ln_s = (const float*)d_in[3];
    const float* ln_b = (const float*)d_in[4];
    const float* w1   = (const float*)d_in[5];
    const float* b1   = (const float*)d_in[6];
    const float* w2   = (const float*)d_in[7];
    const float* b2   = (const float*)d_in[8];

    float* logits = (float*)d_out;            // [NB]
    float* g_out  = (float*)d_out + NB;       // [NB, NE]

    char* ws = (char*)d_ws;
    unsigned short* xn = (unsigned short*)(ws + WS_XN_OFF);
    int* cnts = (int*)(ws + WS_CNT_OFF);
    int* rowl = (int*)(ws + WS_ROWS_OFF);

    hipMemsetAsync(cnts, 0, 256, stream);

    gate_ln_kernel<<<NB / 4, 256, 0, stream>>>(z, gw, gb, ln_s, ln_b, b2,
                                               xn, cnts, rowl, g_out, logits);
    mfma_mlp<<<NE * NCH, 512, 0, stream>>>(xn, w1, b1, w2, cnts, rowl, logits);
}

// Round 5
// 257.980 us; speedup vs baseline: 1.8567x; 1.8567x over previous
//
#include <hip/hip_runtime.h>
#include <math.h>

#define NB 16384
#define ND 512
#define NE 16
#define NH 2048
#define BM 256            // rows per tile
#define BN 128            // cols per block chunk
#define BK 64             // k per pipeline step
#define NCH (NH / BN)     // 16 col chunks
#define NTB 4             // row-tile grid stride
#define LN_EPS 1e-5f

typedef __attribute__((ext_vector_type(8))) short s8v;   // 8 bf16
typedef __attribute__((ext_vector_type(4))) float f4v;   // mfma acc

// ---- ws layout (bytes) ----
#define WS_XN_OFF   ((size_t)0)
#define WS_XN_BYTES ((size_t)NB * ND * 2)                 // 16 MiB
#define WS_MU_OFF   (WS_XN_OFF + WS_XN_BYTES)
#define WS_RSTD_OFF (WS_MU_OFF + (size_t)NB * 4)
#define WS_IDX_OFF  (WS_RSTD_OFF + (size_t)NB * 4)
#define WS_CNT_OFF  (WS_IDX_OFF + (size_t)NB * 4)
#define WS_ROWS_OFF (WS_CNT_OFF + 256)

__device__ __forceinline__ unsigned short bf16_rne(float f) {
    unsigned u = __float_as_uint(f);
    unsigned r = (u + 0x7fffu + ((u >> 16) & 1u)) >> 16;
    return (unsigned short)r;
}

// ---------------- Kernel 1: gate + softmax + argmax + LN stats ------------
// One wave per row. lane = q(expert group, 0..3) x dg(d-group, 0..15).
// Lane computes 4 expert dots over 32 d's -> 4-level dg butterfly ->
// 2-level q reduce for softmax. 24 shuffles total (vs 108 before).
__global__ __launch_bounds__(256) void gate_kernel(
    const float* __restrict__ z, const float* __restrict__ gw,
    const float* __restrict__ gb, const float* __restrict__ b2,
    float* __restrict__ mu_ws, float* __restrict__ rstd_ws,
    int* __restrict__ idx_ws, float* __restrict__ g_out,
    float* __restrict__ logits)
{
    int wave = threadIdx.x >> 6;
    int lane = threadIdx.x & 63;
    int b = blockIdx.x * 4 + wave;
    int q = lane & 3, dg = lane >> 2;

    const float* zr = z + (size_t)b * ND;
    float4 zv[8];
#pragma unroll
    for (int i = 0; i < 8; ++i)
        zv[i] = *reinterpret_cast<const float4*>(zr + dg * 32 + i * 4);

    float sum = 0.f, ssq = 0.f;
    float ga[4] = {0.f, 0.f, 0.f, 0.f};
#pragma unroll
    for (int i = 0; i < 8; ++i) {
        float zs[4] = {zv[i].x, zv[i].y, zv[i].z, zv[i].w};
#pragma unroll
        for (int t = 0; t < 4; ++t) {
            int d = dg * 32 + i * 4 + t;
            float4 w4 = *reinterpret_cast<const float4*>(gw + (size_t)d * NE + q * 4);
            ga[0] = fmaf(zs[t], w4.x, ga[0]);
            ga[1] = fmaf(zs[t], w4.y, ga[1]);
            ga[2] = fmaf(zs[t], w4.z, ga[2]);
            ga[3] = fmaf(zs[t], w4.w, ga[3]);
            sum += zs[t];
            ssq = fmaf(zs[t], zs[t], ssq);
        }
    }
    // reduce over dg (bits 2..5)
#pragma unroll
    for (int m = 4; m <= 32; m <<= 1) {
        sum += __shfl_xor(sum, m);
        ssq += __shfl_xor(ssq, m);
#pragma unroll
        for (int j = 0; j < 4; ++j) ga[j] += __shfl_xor(ga[j], m);
    }
#pragma unroll
    for (int j = 0; j < 4; ++j) ga[j] += gb[q * 4 + j];

    float mu = sum * (1.f / ND);
    float var = ssq * (1.f / ND) - mu * mu;
    float rstd = rsqrtf(var + LN_EPS);

    // softmax over 16 experts: local max/sum + 2-level q reduce
    float lmax = fmaxf(fmaxf(ga[0], ga[1]), fmaxf(ga[2], ga[3]));
    lmax = fmaxf(lmax, __shfl_xor(lmax, 1));
    lmax = fmaxf(lmax, __shfl_xor(lmax, 2));
    float ge[4], lsum = 0.f;
#pragma unroll
    for (int j = 0; j < 4; ++j) { ge[j] = __expf(ga[j] - lmax); lsum += ge[j]; }
    lsum += __shfl_xor(lsum, 1);
    lsum += __shfl_xor(lsum, 2);
    float rden = 1.f / lsum;

    // argmax first-occurrence
    int li = 1000;
#pragma unroll
    for (int j = 3; j >= 0; --j) if (ga[j] == lmax) li = q * 4 + j;
    li = min(li, __shfl_xor(li, 1));
    li = min(li, __shfl_xor(li, 2));

    // g write: lane l<16 wants expert l = (l>>2)*4 + (l&3)
    float gv0 = ge[0] * rden, gv1 = ge[1] * rden, gv2 = ge[2] * rden, gv3 = ge[3] * rden;
    int srcl = lane >> 2;
    float t0 = __shfl(gv0, srcl), t1 = __shfl(gv1, srcl);
    float t2 = __shfl(gv2, srcl), t3 = __shfl(gv3, srcl);
    float gval = (q == 0) ? t0 : (q == 1) ? t1 : (q == 2) ? t2 : t3;
    if (lane < NE) g_out[(size_t)b * NE + lane] = gval;

    if (lane == 0) {
        mu_ws[b] = mu;
        rstd_ws[b] = rstd;
        idx_ws[b] = li;
        logits[b] = b2[li];   // init; mfma_mlp accumulates on top
    }
}

// ---------------- Kernel 2: bucket build (deterministic, no atomics) ------
// 16 blocks x 1 wave. Block e scans idx[] ascending, ballot-compacts.
__global__ __launch_bounds__(64) void bucket_kernel(
    const int* __restrict__ idx_ws, int* __restrict__ counts,
    int* __restrict__ rows)
{
    int e = blockIdx.x;
    int lane = threadIdx.x;
    int cnt = 0;
    unsigned long long below = (lane == 0) ? 0ull : ((~0ull) >> (64 - lane));
    for (int base = 0; base < NB; base += 64) {
        int v = idx_ws[base + lane];
        unsigned long long m = __ballot(v == e);
        if (v == e) rows[(size_t)e * NB + cnt + __popcll(m & below)] = base + lane;
        cnt += __popcll(m);
    }
    if (lane == 0) counts[e] = cnt;
}

// ---------------- Kernel 3: xn = LN(z)*ln_s[idx]+ln_b[idx] (bf16) ---------
__global__ __launch_bounds__(256) void xn_kernel(
    const float* __restrict__ z, const float* __restrict__ ln_s,
    const float* __restrict__ ln_b, const float* __restrict__ mu_ws,
    const float* __restrict__ rstd_ws, const int* __restrict__ idx_ws,
    unsigned short* __restrict__ xn)
{
    int wave = threadIdx.x >> 6;
    int lane = threadIdx.x & 63;
    int b = blockIdx.x * 4 + wave;
    int e = idx_ws[b];
    float mu = mu_ws[b], rstd = rstd_ws[b];

    const float* zr = z + (size_t)b * ND + lane * 8;
    const float* ls = ln_s + (size_t)e * ND + lane * 8;
    const float* lb = ln_b + (size_t)e * ND + lane * 8;
    float4 z0 = *reinterpret_cast<const float4*>(zr);
    float4 z1 = *reinterpret_cast<const float4*>(zr + 4);
    float4 s0 = *reinterpret_cast<const float4*>(ls);
    float4 s1 = *reinterpret_cast<const float4*>(ls + 4);
    float4 t0 = *reinterpret_cast<const float4*>(lb);
    float4 t1 = *reinterpret_cast<const float4*>(lb + 4);
    float zv[8] = {z0.x, z0.y, z0.z, z0.w, z1.x, z1.y, z1.z, z1.w};
    float sv[8] = {s0.x, s0.y, s0.z, s0.w, s1.x, s1.y, s1.z, s1.w};
    float bv[8] = {t0.x, t0.y, t0.z, t0.w, t1.x, t1.y, t1.z, t1.w};
    unsigned short xb[8];
#pragma unroll
    for (int k = 0; k < 8; ++k)
        xb[k] = bf16_rne((zv[k] - mu) * rstd * sv[k] + bv[k]);
    *reinterpret_cast<s8v*>(xn + (size_t)b * ND + lane * 8) =
        *reinterpret_cast<s8v*>(xb);
}

// ---------------- Kernel 4: pipelined grouped MFMA GEMM -------------------
// grid = 16e x 16ch x 4tb = 1024; e = bid&15 (XCD pinning).
// Tile: 256 rows x 128 cols, K stepped by 64, A+B double-buffered LDS
// (96 KiB). 8 waves as 4(M) x 2(N), each wave 64x64 out (4x4 frags,
// reads/MFMA = 0.5). A staged via global_load_lds (linear dest,
// inverse-swizzled per-lane source); B reg-staged f32->bf16 with swizzled
// ds_write. stage(s+1) overlaps compute(s); one barrier per K-step.
__global__ __launch_bounds__(512, 2) void mfma_mlp(
    const unsigned short* __restrict__ xn, const float* __restrict__ w1,
    const float* __restrict__ b1, const float* __restrict__ w2,
    const int* __restrict__ counts, const int* __restrict__ rows,
    float* __restrict__ logits)
{
    __shared__ unsigned short A_lds[2][BM * BK];   // 2 x 32 KiB
    __shared__ unsigned short B_lds[2][BN * BK];   // 2 x 16 KiB

    int bid = blockIdx.x;
    int e = bid & 15;
    int rest = bid >> 4;
    int ch = rest & 15;
    int tb0 = rest >> 4;
    int c0 = ch * BN;
    int tid = threadIdx.x, lane = tid & 63, wave = tid >> 6;
    int wm = wave & 3, wn = wave >> 2;
    int cnt = counts[e];
    const int* rl = rows + (size_t)e * NB;

    float b1v[4], w2v[4];
#pragma unroll
    for (int cf = 0; cf < 4; ++cf) {
        int col = c0 + wn * 64 + cf * 16 + (lane & 15);
        b1v[cf] = b1[(size_t)e * NH + col];
        w2v[cf] = w2[(size_t)e * NH + col];
    }

    int g = lane >> 4;
    int swz = (lane & 7) << 4;          // frag-read swizzle (row&7 == lane&7)

    // B staging coords: col bc, k-subgroup bkg
    int bc = tid & 127;
    int bkg = tid >> 7;                 // 0..3 -> k offset bkg*16
    const float* w1base = w1 + (size_t)e * ND * NH + c0 + bc;
    char* bcol0 = (char*)&B_lds[0][0] + bc * 128;
    char* bcol1 = (char*)&B_lds[1][0] + bc * 128;
    int bko = bkg * 32;                 // byte offset of this thread's k-run
    int bsw = (bc & 7) << 4;

    // A staging coords
    int aseg = lane >> 3;               // row within 8-row segment
    int abo = (lane & 7) * 16;          // byte within row

    for (int tb = tb0; tb * BM < cnt; tb += NTB) {
        int rbase = tb * BM;

        // ---------- prologue: stage step 0 into buffers 0 ----------
        {
#pragma unroll
            for (int i = 0; i < 4; ++i) {
                int rloc = (wave * 4 + i) * 8 + aseg;
                int rg = rl[min(rbase + rloc, cnt - 1)];
                const char* asrc = (const char*)(xn + (size_t)rg * ND)
                                   + (abo ^ ((rloc & 7) << 4));
                unsigned short* dst = &A_lds[0][(wave * 4 + i) * 8 * BK];
                __builtin_amdgcn_global_load_lds(
                    (const __attribute__((address_space(1))) void*)asrc,
                    (__attribute__((address_space(3))) void*)dst, 16, 0, 0);
            }
            float bf[16];
            const float* bsrc = w1base + (size_t)(bkg * 16) * NH;
#pragma unroll
            for (int j = 0; j < 16; ++j) bf[j] = bsrc[(size_t)j * NH];
            unsigned int u[8];
#pragma unroll
            for (int p = 0; p < 8; ++p)
                u[p] = (unsigned)bf16_rne(bf[2 * p]) |
                       ((unsigned)bf16_rne(bf[2 * p + 1]) << 16);
            *reinterpret_cast<uint4*>(bcol0 + (bko ^ bsw)) =
                make_uint4(u[0], u[1], u[2], u[3]);
            *reinterpret_cast<uint4*>(bcol0 + ((bko + 16) ^ bsw)) =
                make_uint4(u[4], u[5], u[6], u[7]);
        }
        __syncthreads();

        f4v acc[4][4];
#pragma unroll
        for (int rf = 0; rf < 4; ++rf)
#pragma unroll
            for (int cf = 0; cf < 4; ++cf) acc[rf][cf] = (f4v){0.f, 0.f, 0.f, 0.f};

#pragma unroll
        for (int s = 0; s < 8; ++s) {
            int cb = s & 1;
            float bf[16];
            if (s < 7) {
                // issue stage for s+1 into cb^1 (overlaps compute below)
#pragma unroll
                for (int i = 0; i < 4; ++i) {
                    int rloc = (wave * 4 + i) * 8 + aseg;
                    int rg = rl[min(rbase + rloc, cnt - 1)];
                    const char* asrc = (const char*)(xn + (size_t)rg * ND)
                                       + (s + 1) * 128 + (abo ^ ((rloc & 7) << 4));
                    unsigned short* dst = &A_lds[cb ^ 1][(wave * 4 + i) * 8 * BK];
                    __builtin_amdgcn_global_load_lds(
                        (const __attribute__((address_space(1))) void*)asrc,
                        (__attribute__((address_space(3))) void*)dst, 16, 0, 0);
                }
                const float* bsrc = w1base + (size_t)((s + 1) * 64 + bkg * 16) * NH;
#pragma unroll
                for (int j = 0; j < 16; ++j) bf[j] = bsrc[(size_t)j * NH];
            }
            // ---- compute on buffer cb ----
#pragma unroll
            for (int ks = 0; ks < 2; ++ks) {
                int kb = (ks * 64 + g * 16) ^ swz;
                s8v a[4], bb[4];
#pragma unroll
                for (int rf = 0; rf < 4; ++rf) {
                    int row = wm * 64 + rf * 16 + (lane & 15);
                    a[rf] = *reinterpret_cast<const s8v*>(
                        (const char*)&A_lds[cb][0] + row * 128 + kb);
                }
#pragma unroll
                for (int cf = 0; cf < 4; ++cf) {
                    int col = wn * 64 + cf * 16 + (lane & 15);
                    bb[cf] = *reinterpret_cast<const s8v*>(
                        (const char*)&B_lds[cb][0] + col * 128 + kb);
                }
#pragma unroll
                for (int rf = 0; rf < 4; ++rf)
#pragma unroll
                    for (int cf = 0; cf < 4; ++cf)
                        acc[rf][cf] = __builtin_amdgcn_mfma_f32_16x16x32_bf16(
                            a[rf], bb[cf], acc[rf][cf], 0, 0, 0);
            }
            if (s < 7) {
                unsigned int u[8];
#pragma unroll
                for (int p = 0; p < 8; ++p)
                    u[p] = (unsigned)bf16_rne(bf[2 * p]) |
                           ((unsigned)bf16_rne(bf[2 * p + 1]) << 16);
                char* bcb = (s & 1) ? bcol0 : bcol1;   // buffer cb^1
                *reinterpret_cast<uint4*>(bcb + (bko ^ bsw)) =
                    make_uint4(u[0], u[1], u[2], u[3]);
                *reinterpret_cast<uint4*>(bcb + ((bko + 16) ^ bsw)) =
                    make_uint4(u[4], u[5], u[6], u[7]);
            }
            __syncthreads();
        }

        // ---- epilogue: bias + gelu + w2 dot + 16-lane reduce + atomic ----
#pragma unroll
        for (int rf = 0; rf < 4; ++rf) {
            float pj[4] = {0.f, 0.f, 0.f, 0.f};
#pragma unroll
            for (int cf = 0; cf < 4; ++cf) {
#pragma unroll
                for (int j = 0; j < 4; ++j) {
                    float h = acc[rf][cf][j] + b1v[cf];
                    float uu = h * (0.7978845608f + 0.0356774081f * h * h);
                    float ex = __expf(2.f * uu);
                    float th = 1.f - 2.f / (ex + 1.f);
                    pj[j] = fmaf(0.5f * h * (1.f + th), w2v[cf], pj[j]);
                }
            }
#pragma unroll
            for (int m = 1; m < 16; m <<= 1)
#pragma unroll
                for (int j = 0; j < 4; ++j) pj[j] += __shfl_xor(pj[j], m);
            if ((lane & 15) == 0) {
#pragma unroll
                for (int j = 0; j < 4; ++j) {
                    int rloc = wm * 64 + rf * 16 + g * 4 + j;
                    if (rbase + rloc < cnt)
                        atomicAdd(&logits[rl[rbase + rloc]], pj[j]);
                }
            }
        }
    }
}

extern "C" void kernel_launch(void* const* d_in, const int* in_sizes, int n_in,
                              void* d_out, int out_size, void* d_ws, size_t ws_size,
                              hipStream_t stream) {
    const float* z    = (const float*)d_in[0];
    const float* gw   = (const float*)d_in[1];
    const float* gb   = (const float*)d_in[2];
    const float* ln_s = (const float*)d_in[3];
    const float* ln_b = (const float*)d_in[4];
    const float* w1   = (const float*)d_in[5];
    const float* b1   = (const float*)d_in[6];
    const float* w2   = (const float*)d_in[7];
    const float* b2   = (const float*)d_in[8];

    float* logits = (float*)d_out;            // [NB]
    float* g_out  = (float*)d_out + NB;       // [NB, NE]

    char* ws = (char*)d_ws;
    unsigned short* xn = (unsigned short*)(ws + WS_XN_OFF);
    float* mu_ws   = (float*)(ws + WS_MU_OFF);
    float* rstd_ws = (float*)(ws + WS_RSTD_OFF);
    int* idx_ws    = (int*)(ws + WS_IDX_OFF);
    int* cnts      = (int*)(ws + WS_CNT_OFF);
    int* rowl      = (int*)(ws + WS_ROWS_OFF);

    gate_kernel<<<NB / 4, 256, 0, stream>>>(z, gw, gb, b2, mu_ws, rstd_ws,
                                            idx_ws, g_out, logits);
    bucket_kernel<<<NE, 64, 0, stream>>>(idx_ws, cnts, rowl);
    xn_kernel<<<NB / 4, 256, 0, stream>>>(z, ln_s, ln_b, mu_ws, rstd_ws,
                                          idx_ws, xn);
    mfma_mlp<<<NE * NCH * NTB, 512, 0, stream>>>(xn, w1, b1, w2, cnts, rowl,
                                                 logits);
}

// Round 6
// 226.740 us; speedup vs baseline: 2.1126x; 1.1378x over previous
//
#include <hip/hip_runtime.h>
#include <math.h>

#define NB 16384
#define ND 512
#define NE 16
#define NH 2048
#define BM 128            // rows per tile
#define BN 128            // cols per tile
#define BK 64             // k per step
#define NCH (NH / BN)     // 16 col chunks
#define NTB 8             // row-tile stride
#define LN_EPS 1e-5f

typedef __attribute__((ext_vector_type(8))) short s8v;   // 8 bf16
typedef __attribute__((ext_vector_type(4))) float f4v;   // mfma acc

// ---- ws layout (bytes) ----
#define WS_W1T_OFF  ((size_t)0)
#define WS_W1T_BYTES ((size_t)NE * NH * ND * 2)           // 32 MiB
#define WS_XN_OFF   (WS_W1T_OFF + WS_W1T_BYTES)
#define WS_XN_BYTES ((size_t)NB * ND * 2)                 // 16 MiB
#define WS_IDX_OFF  (WS_XN_OFF + WS_XN_BYTES)
#define WS_CNT_OFF  (WS_IDX_OFF + (size_t)NB * 4)
#define WS_ROWS_OFF (WS_CNT_OFF + 256)

__device__ __forceinline__ unsigned short bf16_rne(float f) {
    unsigned u = __float_as_uint(f);
    unsigned r = (u + 0x7fffu + ((u >> 16) & 1u)) >> 16;
    return (unsigned short)r;
}

// ---------------- Kernel A: w1 [E][D][H] f32 -> w1t [E][H][D] bf16 --------
// No LDS: thread t owns output row h=hb*256+t; reads column (64 d's) via
// 64 wave-coalesced 1KB loads; writes 128 B contiguous. grid 16e*8db*8hb.
__global__ __launch_bounds__(256) void w1conv_kernel(
    const float* __restrict__ w1, unsigned short* __restrict__ w1t)
{
    int bid = blockIdx.x;
    int e = bid & 15;
    int rest = bid >> 4;
    int db = rest & 7;
    int hb = rest >> 3;
    int h = hb * 256 + threadIdx.x;

    const float* src = w1 + ((size_t)e * ND + db * 64) * NH + h;
    unsigned int u[32];
#pragma unroll
    for (int p = 0; p < 32; ++p) {
        float f0 = src[(size_t)(2 * p) * NH];
        float f1 = src[(size_t)(2 * p + 1) * NH];
        u[p] = (unsigned)bf16_rne(f0) | ((unsigned)bf16_rne(f1) << 16);
    }
    uint4* dst = reinterpret_cast<uint4*>(
        w1t + ((size_t)e * NH + h) * ND + db * 64);
#pragma unroll
    for (int p = 0; p < 8; ++p)
        dst[p] = make_uint4(u[4 * p], u[4 * p + 1], u[4 * p + 2], u[4 * p + 3]);
}

// ---------------- Kernel B: gate + softmax + argmax + LN + xn(bf16) -------
// One wave per row. lane = q(expert group,0..3) x dg(d-group,0..15).
__global__ __launch_bounds__(256) void gate_ln_kernel(
    const float* __restrict__ z, const float* __restrict__ gw,
    const float* __restrict__ gb, const float* __restrict__ ln_s,
    const float* __restrict__ ln_b, const float* __restrict__ b2,
    unsigned short* __restrict__ xn, int* __restrict__ idx_ws,
    float* __restrict__ g_out, float* __restrict__ logits)
{
    int wave = threadIdx.x >> 6;
    int lane = threadIdx.x & 63;
    int b = blockIdx.x * 4 + wave;
    int q = lane & 3, dg = lane >> 2;

    const float* zr = z + (size_t)b * ND;
    float4 zv[8];
#pragma unroll
    for (int i = 0; i < 8; ++i)
        zv[i] = *reinterpret_cast<const float4*>(zr + dg * 32 + i * 4);

    float sum = 0.f, ssq = 0.f;
    float ga[4] = {0.f, 0.f, 0.f, 0.f};
#pragma unroll
    for (int i = 0; i < 8; ++i) {
        float zs[4] = {zv[i].x, zv[i].y, zv[i].z, zv[i].w};
#pragma unroll
        for (int t = 0; t < 4; ++t) {
            int d = dg * 32 + i * 4 + t;
            float4 w4 = *reinterpret_cast<const float4*>(gw + (size_t)d * NE + q * 4);
            ga[0] = fmaf(zs[t], w4.x, ga[0]);
            ga[1] = fmaf(zs[t], w4.y, ga[1]);
            ga[2] = fmaf(zs[t], w4.z, ga[2]);
            ga[3] = fmaf(zs[t], w4.w, ga[3]);
            sum += zs[t];
            ssq = fmaf(zs[t], zs[t], ssq);
        }
    }
#pragma unroll
    for (int m = 4; m <= 32; m <<= 1) {
        sum += __shfl_xor(sum, m);
        ssq += __shfl_xor(ssq, m);
#pragma unroll
        for (int j = 0; j < 4; ++j) ga[j] += __shfl_xor(ga[j], m);
    }
#pragma unroll
    for (int j = 0; j < 4; ++j) ga[j] += gb[q * 4 + j];

    float mu = sum * (1.f / ND);
    float var = ssq * (1.f / ND) - mu * mu;
    float rstd = rsqrtf(var + LN_EPS);

    float lmax = fmaxf(fmaxf(ga[0], ga[1]), fmaxf(ga[2], ga[3]));
    lmax = fmaxf(lmax, __shfl_xor(lmax, 1));
    lmax = fmaxf(lmax, __shfl_xor(lmax, 2));
    float ge[4], lsum = 0.f;
#pragma unroll
    for (int j = 0; j < 4; ++j) { ge[j] = __expf(ga[j] - lmax); lsum += ge[j]; }
    lsum += __shfl_xor(lsum, 1);
    lsum += __shfl_xor(lsum, 2);
    float rden = 1.f / lsum;

    int li = 1000;
#pragma unroll
    for (int j = 3; j >= 0; --j) if (ga[j] == lmax) li = q * 4 + j;
    li = min(li, __shfl_xor(li, 1));
    li = min(li, __shfl_xor(li, 2));

    // g write: lane l<16 wants expert l = (l>>2)*4 + (l&3)
    float gv0 = ge[0] * rden, gv1 = ge[1] * rden;
    float gv2 = ge[2] * rden, gv3 = ge[3] * rden;
    int srcl = lane >> 2;
    float t0 = __shfl(gv0, srcl), t1 = __shfl(gv1, srcl);
    float t2 = __shfl(gv2, srcl), t3 = __shfl(gv3, srcl);
    float gval = (q == 0) ? t0 : (q == 1) ? t1 : (q == 2) ? t2 : t3;
    if (lane < NE) g_out[(size_t)b * NE + lane] = gval;

    // xn: lane writes d = dg*32 + q*8 .. +8 (16B), from zv[2q], zv[2q+1]
    float4 xa, xc;
    if (q == 0)      { xa = zv[0]; xc = zv[1]; }
    else if (q == 1) { xa = zv[2]; xc = zv[3]; }
    else if (q == 2) { xa = zv[4]; xc = zv[5]; }
    else             { xa = zv[6]; xc = zv[7]; }
    int dofs = dg * 32 + q * 8;
    const float* ls = ln_s + (size_t)li * ND + dofs;
    const float* lb = ln_b + (size_t)li * ND + dofs;
    float4 s0 = *reinterpret_cast<const float4*>(ls);
    float4 s1 = *reinterpret_cast<const float4*>(ls + 4);
    float4 u0 = *reinterpret_cast<const float4*>(lb);
    float4 u1 = *reinterpret_cast<const float4*>(lb + 4);
    unsigned short xb[8];
    xb[0] = bf16_rne((xa.x - mu) * rstd * s0.x + u0.x);
    xb[1] = bf16_rne((xa.y - mu) * rstd * s0.y + u0.y);
    xb[2] = bf16_rne((xa.z - mu) * rstd * s0.z + u0.z);
    xb[3] = bf16_rne((xa.w - mu) * rstd * s0.w + u0.w);
    xb[4] = bf16_rne((xc.x - mu) * rstd * s1.x + u1.x);
    xb[5] = bf16_rne((xc.y - mu) * rstd * s1.y + u1.y);
    xb[6] = bf16_rne((xc.z - mu) * rstd * s1.z + u1.z);
    xb[7] = bf16_rne((xc.w - mu) * rstd * s1.w + u1.w);
    *reinterpret_cast<s8v*>(xn + (size_t)b * ND + dofs) =
        *reinterpret_cast<s8v*>(xb);

    if (lane == 0) {
        idx_ws[b] = li;
        logits[b] = b2[li];   // init; mfma_mlp accumulates on top
    }
}

// ---------------- Kernel C: bucket build (int4 ballot-compact) ------------
__global__ __launch_bounds__(64) void bucket_kernel(
    const int* __restrict__ idx_ws, int* __restrict__ counts,
    int* __restrict__ rows)
{
    int e = blockIdx.x;
    int lane = threadIdx.x;
    int cnt = 0;
    unsigned long long below = (lane == 0) ? 0ull : ((~0ull) >> (64 - lane));
    const int4* p = reinterpret_cast<const int4*>(idx_ws);
    int* re = rows + (size_t)e * NB;
#pragma unroll 2
    for (int base = 0; base < NB / 4; base += 64) {
        int4 v = p[base + lane];
        int vv[4] = {v.x, v.y, v.z, v.w};
#pragma unroll
        for (int k = 0; k < 4; ++k) {
            unsigned long long m = __ballot(vv[k] == e);
            if (vv[k] == e)
                re[cnt + __popcll(m & below)] = (base + lane) * 4 + k;
            cnt += __popcll(m);
        }
    }
    if (lane == 0) counts[e] = cnt;
}

// ---------------- Kernel D: m97-style grouped MFMA GEMM ------------------
// grid = 16e x 16ch x 8tb = 2048; e = bid&15 (XCD pinning).
// 128x128 tile, BK=64, 32 KiB LDS single-buffer, 256 thr (4 waves as 2x2,
// wave tile 64x64). A and B both staged by global_load_lds width=16 with
// source-side XOR pre-swizzle (linear LDS dest); 2 barriers per K-step;
// 4 blocks/CU for cross-block latency hiding (m114 mechanism).
__global__ __launch_bounds__(256, 4) void mfma_mlp(
    const unsigned short* __restrict__ xn, const unsigned short* __restrict__ w1t,
    const float* __restrict__ b1, const float* __restrict__ w2,
    const int* __restrict__ counts, const int* __restrict__ rows,
    float* __restrict__ logits)
{
    __shared__ unsigned short A_lds[BM * BK];   // 16 KiB
    __shared__ unsigned short B_lds[BN * BK];   // 16 KiB

    int bid = blockIdx.x;
    int e = bid & 15;
    int rest = bid >> 4;
    int ch = rest & 15;
    int tb0 = rest >> 4;
    int c0 = ch * BN;
    int tid = threadIdx.x, lane = tid & 63, wave = tid >> 6;
    int wm = wave & 1, wn = wave >> 1;
    int cnt = counts[e];
    const int* rl = rows + (size_t)e * NB;

    int rquad = lane >> 3;              // 0..7
    int bbyte = (lane & 7) * 16;
    int sbyte = bbyte ^ (rquad << 4);   // source byte w/ pre-swizzle

    // B source byte offsets (row bases constant across steps/tiles)
    size_t boff[4];
#pragma unroll
    for (int i = 0; i < 4; ++i) {
        int cl = (wave * 4 + i) * 8 + rquad;
        boff[i] = ((size_t)(e * NH + c0 + cl) * ND) * 2 + sbyte;
    }

    float b1v[4], w2v[4];
#pragma unroll
    for (int cf = 0; cf < 4; ++cf) {
        int col = c0 + wn * 64 + cf * 16 + (lane & 15);
        b1v[cf] = b1[(size_t)e * NH + col];
        w2v[cf] = w2[(size_t)e * NH + col];
    }

    int g = lane >> 4;
    int fr = lane & 15;
    int sw = (lane & 7) << 4;
    // LDS read byte offsets
    int aoffs[4], boffs[4];
#pragma unroll
    for (int f = 0; f < 4; ++f) {
        aoffs[f] = (wm * 64 + f * 16 + fr) * 128;
        boffs[f] = (wn * 64 + f * 16 + fr) * 128;
    }

    for (int tb = tb0; tb * BM < cnt; tb += NTB) {
        int rbase = tb * BM;

        // A source offsets for this tile
        size_t aoff[4];
#pragma unroll
        for (int i = 0; i < 4; ++i) {
            int rloc = (wave * 4 + i) * 8 + rquad;
            int rg = rl[min(rbase + rloc, cnt - 1)];
            aoff[i] = (size_t)rg * (ND * 2) + sbyte;
        }

        __syncthreads();   // previous tile's reads done before restage

        // stage step 0
#pragma unroll
        for (int i = 0; i < 4; ++i) {
            __builtin_amdgcn_global_load_lds(
                (const __attribute__((address_space(1))) void*)((const char*)xn + aoff[i]),
                (__attribute__((address_space(3))) void*)&A_lds[(wave * 4 + i) * 8 * BK],
                16, 0, 0);
            __builtin_amdgcn_global_load_lds(
                (const __attribute__((address_space(1))) void*)((const char*)w1t + boff[i]),
                (__attribute__((address_space(3))) void*)&B_lds[(wave * 4 + i) * 8 * BK],
                16, 0, 0);
        }

        f4v acc[4][4];
#pragma unroll
        for (int rf = 0; rf < 4; ++rf)
#pragma unroll
            for (int cf = 0; cf < 4; ++cf) acc[rf][cf] = (f4v){0.f, 0.f, 0.f, 0.f};

#pragma unroll
        for (int s = 0; s < 8; ++s) {
            __syncthreads();   // staging of step s complete
            s8v a[4], bb[4];
#pragma unroll
            for (int ks = 0; ks < 2; ++ks) {
                int kb = (ks * 64 + g * 16) ^ sw;
#pragma unroll
                for (int rf = 0; rf < 4; ++rf)
                    a[rf] = *reinterpret_cast<const s8v*>(
                        (const char*)A_lds + aoffs[rf] + kb);
#pragma unroll
                for (int cf = 0; cf < 4; ++cf)
                    bb[cf] = *reinterpret_cast<const s8v*>(
                        (const char*)B_lds + boffs[cf] + kb);
#pragma unroll
                for (int rf = 0; rf < 4; ++rf)
#pragma unroll
                    for (int cf = 0; cf < 4; ++cf)
                        acc[rf][cf] = __builtin_amdgcn_mfma_f32_16x16x32_bf16(
                            a[rf], bb[cf], acc[rf][cf], 0, 0, 0);
            }
            if (s < 7) {
                __syncthreads();   // all reads of step s done; restage
#pragma unroll
                for (int i = 0; i < 4; ++i) {
                    __builtin_amdgcn_global_load_lds(
                        (const __attribute__((address_space(1))) void*)
                            ((const char*)xn + aoff[i] + (s + 1) * 128),
                        (__attribute__((address_space(3))) void*)
                            &A_lds[(wave * 4 + i) * 8 * BK],
                        16, 0, 0);
                    __builtin_amdgcn_global_load_lds(
                        (const __attribute__((address_space(1))) void*)
                            ((const char*)w1t + boff[i] + (s + 1) * 128),
                        (__attribute__((address_space(3))) void*)
                            &B_lds[(wave * 4 + i) * 8 * BK],
                        16, 0, 0);
                }
            }
        }

        // ---- epilogue: bias + gelu + w2 dot + 16-lane reduce + atomic ----
#pragma unroll
        for (int rf = 0; rf < 4; ++rf) {
            float pj[4] = {0.f, 0.f, 0.f, 0.f};
#pragma unroll
            for (int cf = 0; cf < 4; ++cf) {
#pragma unroll
                for (int j = 0; j < 4; ++j) {
                    float h = acc[rf][cf][j] + b1v[cf];
                    float uu = h * (0.7978845608f + 0.0356774081f * h * h);
                    float ex = __expf(2.f * uu);
                    float th = 1.f - 2.f / (ex + 1.f);
                    pj[j] = fmaf(0.5f * h * (1.f + th), w2v[cf], pj[j]);
                }
            }
#pragma unroll
            for (int m = 1; m < 16; m <<= 1)
#pragma unroll
                for (int j = 0; j < 4; ++j) pj[j] += __shfl_xor(pj[j], m);
            if ((lane & 15) == 0) {
#pragma unroll
                for (int j = 0; j < 4; ++j) {
                    int rloc = wm * 64 + rf * 16 + g * 4 + j;
                    if (rbase + rloc < cnt)
                        atomicAdd(&logits[rl[rbase + rloc]], pj[j]);
                }
            }
        }
    }
}

extern "C" void kernel_launch(void* const* d_in, const int* in_sizes, int n_in,
                              void* d_out, int out_size, void* d_ws, size_t ws_size,
                              hipStream_t stream) {
    const float* z    = (const float*)d_in[0];
    const float* gw   = (const float*)d_in[1];
    const float* gb   = (const float*)d_in[2];
    const float* ln_s = (const float*)d_in[3];
    const float* ln_b = (const float*)d_in[4];
    const float* w1   = (const float*)d_in[5];
    const float* b1   = (const float*)d_in[6];
    const float* w2   = (const float*)d_in[7];
    const float* b2   = (const float*)d_in[8];

    float* logits = (float*)d_out;            // [NB]
    float* g_out  = (float*)d_out + NB;       // [NB, NE]

    char* ws = (char*)d_ws;
    unsigned short* w1t = (unsigned short*)(ws + WS_W1T_OFF);
    unsigned short* xn  = (unsigned short*)(ws + WS_XN_OFF);
    int* idx_ws = (int*)(ws + WS_IDX_OFF);
    int* cnts   = (int*)(ws + WS_CNT_OFF);
    int* rowl   = (int*)(ws + WS_ROWS_OFF);

    w1conv_kernel<<<NE * 64, 256, 0, stream>>>(w1, w1t);
    gate_ln_kernel<<<NB / 4, 256, 0, stream>>>(z, gw, gb, ln_s, ln_b, b2,
                                               xn, idx_ws, g_out, logits);
    bucket_kernel<<<NE, 64, 0, stream>>>(idx_ws, cnts, rowl);
    mfma_mlp<<<NE * NCH * NTB, 256, 0, stream>>>(xn, w1t, b1, w2, cnts, rowl,
                                                 logits);
}

// Round 7
// 175.333 us; speedup vs baseline: 2.7319x; 1.2932x over previous
//
#include <hip/hip_runtime.h>
#include <math.h>

#define NB 16384
#define ND 512
#define NE 16
#define NH 2048
#define BM 128            // rows per tile
#define BN 128            // cols per tile
#define BK 64             // k per step
#define NCH (NH / BN)     // 16 col chunks
#define NTB 8             // row-tile stride
#define LN_EPS 1e-5f

typedef __attribute__((ext_vector_type(8))) short s8v;   // 8 bf16
typedef __attribute__((ext_vector_type(4))) float f4v;   // mfma acc

// ---- ws layout (bytes) ----
#define WS_W1T_OFF  ((size_t)0)
#define WS_W1T_BYTES ((size_t)NE * NH * ND * 2)           // 32 MiB
#define WS_XN_OFF   (WS_W1T_OFF + WS_W1T_BYTES)
#define WS_XN_BYTES ((size_t)NB * ND * 2)                 // 16 MiB
#define WS_IDX_OFF  (WS_XN_OFF + WS_XN_BYTES)
#define WS_CNT_OFF  (WS_IDX_OFF + (size_t)NB * 4)
#define WS_ROWS_OFF (WS_CNT_OFF + 256)

__device__ __forceinline__ unsigned short bf16_rne(float f) {
    unsigned u = __float_as_uint(f);
    unsigned r = (u + 0x7fffu + ((u >> 16) & 1u)) >> 16;
    return (unsigned short)r;
}

// ---------------- Kernel A: w1 [E][D][H] f32 -> w1t [E][H][D] bf16 --------
__global__ __launch_bounds__(256) void w1conv_kernel(
    const float* __restrict__ w1, unsigned short* __restrict__ w1t)
{
    int bid = blockIdx.x;
    int e = bid & 15;
    int rest = bid >> 4;
    int db = rest & 7;
    int hb = rest >> 3;
    int h = hb * 256 + threadIdx.x;

    const float* src = w1 + ((size_t)e * ND + db * 64) * NH + h;
    unsigned int u[32];
#pragma unroll
    for (int p = 0; p < 32; ++p) {
        float f0 = src[(size_t)(2 * p) * NH];
        float f1 = src[(size_t)(2 * p + 1) * NH];
        u[p] = (unsigned)bf16_rne(f0) | ((unsigned)bf16_rne(f1) << 16);
    }
    uint4* dst = reinterpret_cast<uint4*>(
        w1t + ((size_t)e * NH + h) * ND + db * 64);
#pragma unroll
    for (int p = 0; p < 8; ++p)
        dst[p] = make_uint4(u[4 * p], u[4 * p + 1], u[4 * p + 2], u[4 * p + 3]);
}

// ---------------- Kernel B: gate + softmax + argmax + LN + xn(bf16) -------
__global__ __launch_bounds__(256) void gate_ln_kernel(
    const float* __restrict__ z, const float* __restrict__ gw,
    const float* __restrict__ gb, const float* __restrict__ ln_s,
    const float* __restrict__ ln_b, const float* __restrict__ b2,
    unsigned short* __restrict__ xn, int* __restrict__ idx_ws,
    float* __restrict__ g_out, float* __restrict__ logits)
{
    int wave = threadIdx.x >> 6;
    int lane = threadIdx.x & 63;
    int b = blockIdx.x * 4 + wave;
    int q = lane & 3, dg = lane >> 2;

    const float* zr = z + (size_t)b * ND;
    float4 zv[8];
#pragma unroll
    for (int i = 0; i < 8; ++i)
        zv[i] = *reinterpret_cast<const float4*>(zr + dg * 32 + i * 4);

    float sum = 0.f, ssq = 0.f;
    float ga[4] = {0.f, 0.f, 0.f, 0.f};
#pragma unroll
    for (int i = 0; i < 8; ++i) {
        float zs[4] = {zv[i].x, zv[i].y, zv[i].z, zv[i].w};
#pragma unroll
        for (int t = 0; t < 4; ++t) {
            int d = dg * 32 + i * 4 + t;
            float4 w4 = *reinterpret_cast<const float4*>(gw + (size_t)d * NE + q * 4);
            ga[0] = fmaf(zs[t], w4.x, ga[0]);
            ga[1] = fmaf(zs[t], w4.y, ga[1]);
            ga[2] = fmaf(zs[t], w4.z, ga[2]);
            ga[3] = fmaf(zs[t], w4.w, ga[3]);
            sum += zs[t];
            ssq = fmaf(zs[t], zs[t], ssq);
        }
    }
#pragma unroll
    for (int m = 4; m <= 32; m <<= 1) {
        sum += __shfl_xor(sum, m);
        ssq += __shfl_xor(ssq, m);
#pragma unroll
        for (int j = 0; j < 4; ++j) ga[j] += __shfl_xor(ga[j], m);
    }
#pragma unroll
    for (int j = 0; j < 4; ++j) ga[j] += gb[q * 4 + j];

    float mu = sum * (1.f / ND);
    float var = ssq * (1.f / ND) - mu * mu;
    float rstd = rsqrtf(var + LN_EPS);

    float lmax = fmaxf(fmaxf(ga[0], ga[1]), fmaxf(ga[2], ga[3]));
    lmax = fmaxf(lmax, __shfl_xor(lmax, 1));
    lmax = fmaxf(lmax, __shfl_xor(lmax, 2));
    float ge[4], lsum = 0.f;
#pragma unroll
    for (int j = 0; j < 4; ++j) { ge[j] = __expf(ga[j] - lmax); lsum += ge[j]; }
    lsum += __shfl_xor(lsum, 1);
    lsum += __shfl_xor(lsum, 2);
    float rden = 1.f / lsum;

    int li = 1000;
#pragma unroll
    for (int j = 3; j >= 0; --j) if (ga[j] == lmax) li = q * 4 + j;
    li = min(li, __shfl_xor(li, 1));
    li = min(li, __shfl_xor(li, 2));

    // g write: lane l<16 wants expert l = (l>>2)*4 + (l&3)
    float gv0 = ge[0] * rden, gv1 = ge[1] * rden;
    float gv2 = ge[2] * rden, gv3 = ge[3] * rden;
    int srcl = lane >> 2;
    float t0 = __shfl(gv0, srcl), t1 = __shfl(gv1, srcl);
    float t2 = __shfl(gv2, srcl), t3 = __shfl(gv3, srcl);
    float gval = (q == 0) ? t0 : (q == 1) ? t1 : (q == 2) ? t2 : t3;
    if (lane < NE) g_out[(size_t)b * NE + lane] = gval;

    // xn: lane writes d = dg*32 + q*8 .. +8 (16B), from zv[2q], zv[2q+1]
    float4 xa, xc;
    if (q == 0)      { xa = zv[0]; xc = zv[1]; }
    else if (q == 1) { xa = zv[2]; xc = zv[3]; }
    else if (q == 2) { xa = zv[4]; xc = zv[5]; }
    else             { xa = zv[6]; xc = zv[7]; }
    int dofs = dg * 32 + q * 8;
    const float* ls = ln_s + (size_t)li * ND + dofs;
    const float* lb = ln_b + (size_t)li * ND + dofs;
    float4 s0 = *reinterpret_cast<const float4*>(ls);
    float4 s1 = *reinterpret_cast<const float4*>(ls + 4);
    float4 u0 = *reinterpret_cast<const float4*>(lb);
    float4 u1 = *reinterpret_cast<const float4*>(lb + 4);
    unsigned short xb[8];
    xb[0] = bf16_rne((xa.x - mu) * rstd * s0.x + u0.x);
    xb[1] = bf16_rne((xa.y - mu) * rstd * s0.y + u0.y);
    xb[2] = bf16_rne((xa.z - mu) * rstd * s0.z + u0.z);
    xb[3] = bf16_rne((xa.w - mu) * rstd * s0.w + u0.w);
    xb[4] = bf16_rne((xc.x - mu) * rstd * s1.x + u1.x);
    xb[5] = bf16_rne((xc.y - mu) * rstd * s1.y + u1.y);
    xb[6] = bf16_rne((xc.z - mu) * rstd * s1.z + u1.z);
    xb[7] = bf16_rne((xc.w - mu) * rstd * s1.w + u1.w);
    *reinterpret_cast<s8v*>(xn + (size_t)b * ND + dofs) =
        *reinterpret_cast<s8v*>(xb);

    if (lane == 0) {
        idx_ws[b] = li;
        logits[b] = b2[li];   // init; mfma_mlp accumulates on top
    }
}

// ---------------- Kernel C: bucket build, 4-wave two-pass -----------------
// Block e: wave w scans quarter w (4096 entries). Pass 1 counts, LDS prefix,
// pass 2 ballot-compacts at the right offset. Deterministic ascending order.
__global__ __launch_bounds__(256) void bucket_kernel(
    const int* __restrict__ idx_ws, int* __restrict__ counts,
    int* __restrict__ rows)
{
    __shared__ int qc[4];
    int e = blockIdx.x;
    int tid = threadIdx.x, w = tid >> 6, lane = tid & 63;
    const int4* p = reinterpret_cast<const int4*>(idx_ws) + (size_t)w * 1024;

    int c = 0;
#pragma unroll 4
    for (int it = 0; it < 16; ++it) {
        int4 v = p[it * 64 + lane];
        c += (v.x == e) + (v.y == e) + (v.z == e) + (v.w == e);
    }
#pragma unroll
    for (int m = 1; m < 64; m <<= 1) c += __shfl_xor(c, m);
    if (lane == 0) qc[w] = c;
    __syncthreads();

    int base = 0;
    for (int j = 0; j < w; ++j) base += qc[j];
    unsigned long long below = (lane == 0) ? 0ull : ((~0ull) >> (64 - lane));
    int* re = rows + (size_t)e * NB;
    int run = base;
#pragma unroll 2
    for (int it = 0; it < 16; ++it) {
        int4 v = p[it * 64 + lane];
        int vv[4] = {v.x, v.y, v.z, v.w};
#pragma unroll
        for (int k = 0; k < 4; ++k) {
            unsigned long long m = __ballot(vv[k] == e);
            if (vv[k] == e)
                re[run + __popcll(m & below)] = w * 4096 + (it * 64 + lane) * 4 + k;
            run += __popcll(m);
        }
    }
    if (tid == 0) counts[e] = qc[0] + qc[1] + qc[2] + qc[3];
}

// ---------------- Kernel D: 2-phase double-buffered grouped MFMA GEMM -----
// grid = 16e x 16ch x 8tb = 2048; e = bid&15 (XCD pinning).
// 128x128 tile, BK=64, A+B double-buffered (64 KiB -> 2 blocks/CU).
// Per step: STAGE(s+1) issued FIRST, then ds_read+MFMA of step s, then ONE
// __syncthreads() (its vmcnt(0) drain sits after ~155 cyc of MFMA -> load
// latency hidden). global_load_lds w=16, source-side XOR pre-swizzle.
__global__ __launch_bounds__(256, 2) void mfma_mlp(
    const unsigned short* __restrict__ xn, const unsigned short* __restrict__ w1t,
    const float* __restrict__ b1, const float* __restrict__ w2,
    const int* __restrict__ counts, const int* __restrict__ rows,
    float* __restrict__ logits)
{
    __shared__ unsigned short A_lds[2][BM * BK];   // 2 x 16 KiB
    __shared__ unsigned short B_lds[2][BN * BK];   // 2 x 16 KiB

    int bid = blockIdx.x;
    int e = bid & 15;
    int rest = bid >> 4;
    int ch = rest & 15;
    int tb0 = rest >> 4;
    int c0 = ch * BN;
    int tid = threadIdx.x, lane = tid & 63, wave = tid >> 6;
    int wm = wave & 1, wn = wave >> 1;
    int cnt = counts[e];
    const int* rl = rows + (size_t)e * NB;

    int rquad = lane >> 3;                       // 0..7
    int sbyte = ((lane & 7) * 16) ^ (rquad << 4);   // pre-swizzled source byte

    // B source byte offsets (constant across tiles)
    size_t boff[4];
#pragma unroll
    for (int i = 0; i < 4; ++i) {
        int cl = (wave * 4 + i) * 8 + rquad;
        boff[i] = ((size_t)(e * NH + c0 + cl) * ND) * 2 + sbyte;
    }

    float b1v[4], w2v[4];
#pragma unroll
    for (int cf = 0; cf < 4; ++cf) {
        int col = c0 + wn * 64 + cf * 16 + (lane & 15);
        b1v[cf] = b1[(size_t)e * NH + col];
        w2v[cf] = w2[(size_t)e * NH + col];
    }

    int g = lane >> 4;
    int fr = lane & 15;
    int sw = (lane & 7) << 4;
    int aoffs[4], boffs[4];                      // LDS read byte offsets
#pragma unroll
    for (int f = 0; f < 4; ++f) {
        aoffs[f] = (wm * 64 + f * 16 + fr) * 128;
        boffs[f] = (wn * 64 + f * 16 + fr) * 128;
    }

    for (int tb = tb0; tb * BM < cnt; tb += NTB) {
        int rbase = tb * BM;

        size_t aoff[4];
#pragma unroll
        for (int i = 0; i < 4; ++i) {
            int rloc = (wave * 4 + i) * 8 + rquad;
            int rg = rl[min(rbase + rloc, cnt - 1)];
            aoff[i] = (size_t)rg * (ND * 2) + sbyte;
        }

        // ---- prologue: stage step 0 into buffers 0 ----
#pragma unroll
        for (int i = 0; i < 4; ++i) {
            __builtin_amdgcn_global_load_lds(
                (const __attribute__((address_space(1))) void*)((const char*)xn + aoff[i]),
                (__attribute__((address_space(3))) void*)&A_lds[0][(wave * 4 + i) * 8 * BK],
                16, 0, 0);
            __builtin_amdgcn_global_load_lds(
                (const __attribute__((address_space(1))) void*)((const char*)w1t + boff[i]),
                (__attribute__((address_space(3))) void*)&B_lds[0][(wave * 4 + i) * 8 * BK],
                16, 0, 0);
        }
        __syncthreads();

        f4v acc[4][4];
#pragma unroll
        for (int rf = 0; rf < 4; ++rf)
#pragma unroll
            for (int cf = 0; cf < 4; ++cf) acc[rf][cf] = (f4v){0.f, 0.f, 0.f, 0.f};

#pragma unroll
        for (int s = 0; s < 8; ++s) {
            int cb = s & 1;
            // issue next-step staging FIRST (in-flight during compute below)
            if (s < 7) {
#pragma unroll
                for (int i = 0; i < 4; ++i) {
                    __builtin_amdgcn_global_load_lds(
                        (const __attribute__((address_space(1))) void*)
                            ((const char*)xn + aoff[i] + (s + 1) * 128),
                        (__attribute__((address_space(3))) void*)
                            &A_lds[cb ^ 1][(wave * 4 + i) * 8 * BK],
                        16, 0, 0);
                    __builtin_amdgcn_global_load_lds(
                        (const __attribute__((address_space(1))) void*)
                            ((const char*)w1t + boff[i] + (s + 1) * 128),
                        (__attribute__((address_space(3))) void*)
                            &B_lds[cb ^ 1][(wave * 4 + i) * 8 * BK],
                        16, 0, 0);
                }
            }
            // ---- compute step s from buffer cb ----
#pragma unroll
            for (int ks = 0; ks < 2; ++ks) {
                int kb = (ks * 64 + g * 16) ^ sw;
                s8v a[4], bb[4];
#pragma unroll
                for (int rf = 0; rf < 4; ++rf)
                    a[rf] = *reinterpret_cast<const s8v*>(
                        (const char*)&A_lds[cb][0] + aoffs[rf] + kb);
#pragma unroll
                for (int cf = 0; cf < 4; ++cf)
                    bb[cf] = *reinterpret_cast<const s8v*>(
                        (const char*)&B_lds[cb][0] + boffs[cf] + kb);
#pragma unroll
                for (int rf = 0; rf < 4; ++rf)
#pragma unroll
                    for (int cf = 0; cf < 4; ++cf)
                        acc[rf][cf] = __builtin_amdgcn_mfma_f32_16x16x32_bf16(
                            a[rf], bb[cf], acc[rf][cf], 0, 0, 0);
            }
            if (s < 7) __syncthreads();   // drains vmcnt: stage(s+1) complete
        }

        // ---- epilogue: bias + gelu + w2 dot + 16-lane reduce + atomic ----
#pragma unroll
        for (int rf = 0; rf < 4; ++rf) {
            float pj[4] = {0.f, 0.f, 0.f, 0.f};
#pragma unroll
            for (int cf = 0; cf < 4; ++cf) {
#pragma unroll
                for (int j = 0; j < 4; ++j) {
                    float h = acc[rf][cf][j] + b1v[cf];
                    float uu = h * (0.7978845608f + 0.0356774081f * h * h);
                    float ex = __expf(2.f * uu);
                    float th = 1.f - 2.f / (ex + 1.f);
                    pj[j] = fmaf(0.5f * h * (1.f + th), w2v[cf], pj[j]);
                }
            }
#pragma unroll
            for (int m = 1; m < 16; m <<= 1)
#pragma unroll
                for (int j = 0; j < 4; ++j) pj[j] += __shfl_xor(pj[j], m);
            if ((lane & 15) == 0) {
#pragma unroll
                for (int j = 0; j < 4; ++j) {
                    int rloc = wm * 64 + rf * 16 + g * 4 + j;
                    if (rbase + rloc < cnt)
                        atomicAdd(&logits[rl[rbase + rloc]], pj[j]);
                }
            }
        }
    }
}

extern "C" void kernel_launch(void* const* d_in, const int* in_sizes, int n_in,
                              void* d_out, int out_size, void* d_ws, size_t ws_size,
                              hipStream_t stream) {
    const float* z    = (const float*)d_in[0];
    const float* gw   = (const float*)d_in[1];
    const float* gb   = (const float*)d_in[2];
    const float* ln_s = (const float*)d_in[3];
    const float* ln_b = (const float*)d_in[4];
    const float* w1   = (const float*)d_in[5];
    const float* b1   = (const float*)d_in[6];
    const float* w2   = (const float*)d_in[7];
    const float* b2   = (const float*)d_in[8];

    float* logits = (float*)d_out;            // [NB]
    float* g_out  = (float*)d_out + NB;       // [NB, NE]

    char* ws = (char*)d_ws;
    unsigned short* w1t = (unsigned short*)(ws + WS_W1T_OFF);
    unsigned short* xn  = (unsigned short*)(ws + WS_XN_OFF);
    int* idx_ws = (int*)(ws + WS_IDX_OFF);
    int* cnts   = (int*)(ws + WS_CNT_OFF);
    int* rowl   = (int*)(ws + WS_ROWS_OFF);

    w1conv_kernel<<<NE * 64, 256, 0, stream>>>(w1, w1t);
    gate_ln_kernel<<<NB / 4, 256, 0, stream>>>(z, gw, gb, ln_s, ln_b, b2,
                                               xn, idx_ws, g_out, logits);
    bucket_kernel<<<NE, 256, 0, stream>>>(idx_ws, cnts, rowl);
    mfma_mlp<<<NE * NCH * NTB, 256, 0, stream>>>(xn, w1t, b1, w2, cnts, rowl,
                                                 logits);
}